// Round 3
// baseline (5772.691 us; speedup 1.0000x reference)
//
#include <hip/hip_runtime.h>
#include <math.h>

#define S_LEN 256
#define BATCH 64
#define NIN   1024
#define NH    2048
#define SCAN_BLOCKS  64    // 32 cols each
#define SCAN_THREADS 512   // 8 waves, K-split 8x256

typedef short s16x8 __attribute__((ext_vector_type(8)));
typedef float f32x4 __attribute__((ext_vector_type(4)));
typedef unsigned short u16x4 __attribute__((ext_vector_type(4)));

__device__ inline unsigned short f2bf(float f){
  unsigned int u = __float_as_uint(f);
  u += 0x7fffu + ((u >> 16) & 1u);      // round-to-nearest-even
  return (unsigned short)(u >> 16);
}

// packed fp32->bf16 RNE (2 elems / instr)
__device__ inline unsigned int pk2(float x, float y){
  unsigned int r;
  asm("v_cvt_pk_bf16_f32 %0, %1, %2" : "=v"(r) : "v"(x), "v"(y));
  return r;
}

// 16B load that bypasses L1/L2 (agent-scope atomic => sc0 sc1, no line fill).
// Used for all reads of addresses that will later be overwritten during the
// scan — a normal load would leave a stale line that sc0/sc1 stores don't fix.
__device__ inline f32x4 load16_bypass(const float* p){
  union { unsigned long long u[2]; f32x4 v; } r;
  r.u[0] = __hip_atomic_load((const unsigned long long*)p,
                             __ATOMIC_RELAXED, __HIP_MEMORY_SCOPE_AGENT);
  r.u[1] = __hip_atomic_load((const unsigned long long*)p + 1,
                             __ATOMIC_RELAXED, __HIP_MEMORY_SCOPE_AGENT);
  return r.v;
}

__global__ void k_cast_bf16(const float* __restrict__ in,
                            unsigned short* __restrict__ out, int n4){
  int i = blockIdx.x * blockDim.x + threadIdx.x;
  if (i >= n4) return;
  float4 v = ((const float4*)in)[i];
  u16x4 o;
  o.x = f2bf(v.x); o.y = f2bf(v.y); o.z = f2bf(v.z); o.w = f2bf(v.w);
  ((u16x4*)out)[i] = o;
}

// out[n][k] = bf16(in[k][n]);  K,N multiples of 32
__global__ void k_transpose_bf16(const float* __restrict__ in,
                                 unsigned short* __restrict__ out, int K, int N){
  __shared__ unsigned short tile[32][33];
  int n0 = blockIdx.x * 32, k0 = blockIdx.y * 32;
  int tx = threadIdx.x, ty = threadIdx.y;   // 32 x 8
  #pragma unroll
  for (int i = 0; i < 4; ++i)
    tile[ty + i*8][tx] = f2bf(in[(size_t)(k0 + ty + i*8) * N + n0 + tx]);
  __syncthreads();
  #pragma unroll
  for (int i = 0; i < 4; ++i)
    out[(size_t)(n0 + ty + i*8) * K + k0 + tx] = tile[tx][ty + i*8];
}

// base = x @ Wx + bx + bh  (fp32 into d_out)
__global__ __launch_bounds__(256) void k_xproj(
    const unsigned short* __restrict__ xbf,   // [16384][1024] bf16
    const unsigned short* __restrict__ wxt,   // [2048][1024]  bf16 (Wx^T)
    const float* __restrict__ bx,
    const float* __restrict__ bh,
    float* __restrict__ out)                  // [16384][2048] fp32
{
  int wave = threadIdx.x >> 6, lane = threadIdx.x & 63;
  int q = lane >> 4, r = lane & 15;
  int m0 = blockIdx.y * 64 + wave * 16;
  int n0 = blockIdx.x * 64;

  const unsigned short* arow = xbf + (size_t)(m0 + r) * NIN + q * 8;
  const unsigned short* brow = wxt + (size_t)(n0 + r) * NIN + q * 8;

  f32x4 acc[4] = {};
  #pragma unroll 2
  for (int kk = 0; kk < NIN; kk += 32){
    s16x8 a = *(const s16x8*)(arow + kk);
    #pragma unroll
    for (int j = 0; j < 4; ++j){
      s16x8 b = *(const s16x8*)(brow + (size_t)j * 16 * NIN + kk);
      acc[j] = __builtin_amdgcn_mfma_f32_16x16x32_bf16(a, b, acc[j], 0, 0, 0);
    }
  }
  #pragma unroll
  for (int j = 0; j < 4; ++j){
    int col = n0 + j * 16 + r;
    float bias = bx[col] + bh[col];
    #pragma unroll
    for (int i = 0; i < 4; ++i){
      int row = m0 + q * 4 + i;
      out[(size_t)row * NH + col] = acc[j][i] + bias;
    }
  }
}

// Persistent weight-stationary scan, v4: maintenance-free coherence (fixed).
// h_t is read as fp32 directly from out[t-1]. h lines are only ever read
// AFTER the producing block's flag (per-wave producer wait) and are never
// written again => every cached copy is fresh => NO per-step acquire fence /
// buffer_inv, and h loads are normal cached loads (XCD L2 shared).
// The two v3 races fixed here:
//  (1) base reads use load16_bypass (sc0 sc1, no L1/L2 allocation) — a normal
//      base load left a stale pre-tanh line that sc0/sc1 epilogue stores do
//      not update, later hit by h-reads of the same addresses.
//  (2) compiler memory fence after the poll loop — relaxed atomic polls do
//      not order the subsequent non-atomic h loads at the IR level.
// Release path: epilogue stores are agent atomic (sc0 sc1 write-through);
// __syncthreads' vmcnt(0) drain puts them at the MALL before the relaxed
// flag store => no buffer_wbl2 anywhere in the loop.
__global__ __launch_bounds__(SCAN_THREADS, 2) void k_scan_persist(
    const float* __restrict__ h0,           // [64][2048] fp32 (input)
    const unsigned short* __restrict__ wht, // [2048][2048] bf16 (Wh^T)
    float* __restrict__ out,                // [256][64][2048] fp32 (base in, tanh out)
    unsigned int* __restrict__ flags)       // 64 flags, stride 4 uints (16B), zeroed
{
  __shared__ float red[8][BATCH][36];

  const int tid = threadIdx.x;
  const int wave = tid >> 6, lane = tid & 63;
  const int q = lane >> 4, r = lane & 15;
  const int n0 = blockIdx.x * 32;
  const int kbase = wave * 256;

  // ---- preload Wh^T slice into registers (once): 2 n-tiles x 8 k-tiles ----
  s16x8 breg[2][8];
  #pragma unroll
  for (int kk = 0; kk < 8; ++kk)
    #pragma unroll
    for (int j = 0; j < 2; ++j)
      breg[j][kk] = *(const s16x8*)(wht + (size_t)(n0 + j*16 + r) * NH + kbase + kk*32 + q*8);

  const int crow = tid >> 3;        // 0..63  (epilogue mapping)
  const int ccol = (tid & 7) * 4;   // 0..28
  const size_t g = (size_t)crow * NH + n0 + ccol;

  // base for t=0: bypassing load (out[0] will be overwritten at step 0)
  f32x4 base = load16_bypass(out + g);

  // this wave's producer flags: blocks 8*wave .. 8*wave+7 (8 lanes, merged)
  const unsigned int* fp = flags + ((((unsigned)wave << 3) | (unsigned)(lane & 7)) << 2);
  // per-lane h offset within a step's h matrix (floats)
  const size_t hoff = (size_t)r * NH + kbase + q * 8;

  for (int t = 0; t < S_LEN; ++t){
    const float* hsrc = (t == 0) ? h0 : out + (size_t)(t - 1) * BATCH * NH;
    float* outT = out + (size_t)t * BATCH * NH;

    // ---- wait: this wave's 8 producers finished step t-1 ----
    if (t > 0){
      const unsigned int target = (unsigned int)t;
      for (;;){
        unsigned int v = __hip_atomic_load(fp, __ATOMIC_RELAXED, __HIP_MEMORY_SCOPE_AGENT);
        if (__all((int)(v >= target))) break;
      }
      asm volatile("" ::: "memory");  // compiler fence: keep h loads below poll
    }

    const float* hp = hsrc + hoff;

    // ---- partial GEMM over this wave's k-range (K=256), fp32 h -> bf16 in-reg ----
    f32x4 acc[4][2] = {};
    #pragma unroll 2
    for (int kk = 0; kk < 8; ++kk){
      s16x8 a[4];
      #pragma unroll
      for (int m = 0; m < 4; ++m){
        const float* p = hp + (size_t)m * 16 * NH + kk * 32;
        f32x4 lo = *(const f32x4*)p;
        f32x4 hi = *(const f32x4*)(p + 4);
        union { unsigned int u[4]; s16x8 v; } c;
        c.u[0] = pk2(lo[0], lo[1]); c.u[1] = pk2(lo[2], lo[3]);
        c.u[2] = pk2(hi[0], hi[1]); c.u[3] = pk2(hi[2], hi[3]);
        a[m] = c.v;
      }
      #pragma unroll
      for (int m = 0; m < 4; ++m)
        #pragma unroll
        for (int j = 0; j < 2; ++j)
          acc[m][j] = __builtin_amdgcn_mfma_f32_16x16x32_bf16(a[m], breg[j][kk], acc[m][j], 0, 0, 0);
    }

    // ---- single-pass K-reduce staging: all 8 waves write partials ----
    #pragma unroll
    for (int m = 0; m < 4; ++m)
      #pragma unroll
      for (int j = 0; j < 2; ++j)
        #pragma unroll
        for (int i = 0; i < 4; ++i)
          red[wave][m*16 + q*4 + i][j*16 + r] = acc[m][j][i];
    __syncthreads();                // (A)

    // ---- epilogue: all 512 threads, 4 elems each ----
    {
      f32x4 s = *(const f32x4*)&red[0][crow][ccol];
      #pragma unroll
      for (int w = 1; w < 8; ++w)
        s += *(const f32x4*)&red[w][crow][ccol];
      float tv[4];
      #pragma unroll
      for (int i = 0; i < 4; ++i) tv[i] = tanhf(base[i] + s[i]);

      union { float f[2]; unsigned long long u; } p0, p1;
      p0.f[0] = tv[0]; p0.f[1] = tv[1];
      p1.f[0] = tv[2]; p1.f[1] = tv[3];
      __hip_atomic_store((unsigned long long*)(outT + g),     p0.u,
                         __ATOMIC_RELAXED, __HIP_MEMORY_SCOPE_AGENT);
      __hip_atomic_store((unsigned long long*)(outT + g) + 1, p1.u,
                         __ATOMIC_RELAXED, __HIP_MEMORY_SCOPE_AGENT);
    }

    __syncthreads();                // (B) vmcnt(0) drain => sc1 stores at MALL;
                                    //     also guards red[] reuse next iter
    if (tid == 0)
      __hip_atomic_store(flags + ((unsigned)blockIdx.x << 2), (unsigned int)(t + 1),
                         __ATOMIC_RELAXED, __HIP_MEMORY_SCOPE_AGENT);

    // prefetch next step's base — bypassing (these addresses get overwritten
    // by this block at step t+1; must not allocate a stale cache line)
    if (t + 1 < S_LEN)
      base = load16_bypass(out + (size_t)(t + 1) * BATCH * NH + g);
  }
}

extern "C" void kernel_launch(void* const* d_in, const int* in_sizes, int n_in,
                              void* d_out, int out_size, void* d_ws, size_t ws_size,
                              hipStream_t stream){
  const float* x  = (const float*)d_in[0];
  const float* h0 = (const float*)d_in[1];
  const float* Wx = (const float*)d_in[2];
  const float* bx = (const float*)d_in[3];
  const float* Wh = (const float*)d_in[4];
  const float* bh = (const float*)d_in[5];
  float* out = (float*)d_out;

  char* ws = (char*)d_ws;
  unsigned short* xbf  = (unsigned short*)(ws);                               // 33,554,432 B
  unsigned short* wxt  = (unsigned short*)(ws + 33554432);                    //  4,194,304 B
  unsigned short* wht  = (unsigned short*)(ws + 33554432 + 4194304);          //  8,388,608 B
  // flag array (64 x 16B) aliases xbf[0..512) — xbf is dead after k_xproj
  unsigned int* flags = (unsigned int*)ws;

  // 1) cast x to bf16
  k_cast_bf16<<<dim3(16384), 256, 0, stream>>>(x, xbf, 4194304);
  // 2) weight transposes to [n][k] bf16
  k_transpose_bf16<<<dim3(NH/32, NIN/32), dim3(32, 8), 0, stream>>>(Wx, wxt, NIN, NH);
  k_transpose_bf16<<<dim3(NH/32, NH/32),  dim3(32, 8), 0, stream>>>(Wh, wht, NH, NH);
  // 3) base = x@Wx + bx + bh -> d_out
  k_xproj<<<dim3(NH/64, (S_LEN*BATCH)/64), 256, 0, stream>>>(xbf, wxt, bx, bh, out);
  // 4) zero flag array (xbf dead now), then persistent scan
  hipMemsetAsync(flags, 0, 1024, stream);
  {
    void* args[] = { (void*)&h0, (void*)&wht, (void*)&out, (void*)&flags };
    hipLaunchCooperativeKernel((const void*)k_scan_persist,
                               dim3(SCAN_BLOCKS), dim3(SCAN_THREADS), args, 0, stream);
  }
  // 5) hn = outputs[255]
  hipMemcpyAsync(out + (size_t)S_LEN * BATCH * NH,
                 out + (size_t)(S_LEN - 1) * BATCH * NH,
                 sizeof(float) * (size_t)BATCH * NH,
                 hipMemcpyDeviceToDevice, stream);
}